// Round 3
// baseline (78.236 us; speedup 1.0000x reference)
//
#include <hip/hip_runtime.h>
#include <math.h>

// S4D kernel generation: K[h,l] = 2*Re( sum_n Ck[h,n] * exp(dtA[h,n]*l) )
// H=1024, N2=32, L=4096. Output (H,L) fp32.
//
// R7 (this round): two-kernel split to attack structural serialization.
//   Evidence: R5 (bank-conflict pad) and R6 (planar packing) each moved only
//   ~1.4us of a ~33us kernel (vs ~3us VALU floor) -> Step-3 micro-efficiency
//   is not the bottleneck; the fp64 prelude convoy (wave 0 of every block on
//   SIMD 0 while 3 waves barrier-wait) + 16 waves/CU occupancy cap are.
//   Kernel A (s4d_prep): 1 thread per (h,n), 32K threads, all fp64 work in
//     parallel; writes w, Ck, w^16, w^2048, (W=w^256, p=2Re W, -q=-|W|^2)
//     to workspace (1.5 MB, L2-resident).
//   Kernel B (s4d_sweep): grid 2H, block (h,s) covers l in [2048s, 2048s+2048);
//     W8^s=w^2048s folded into P-chain start (fp64-accurate from kernel A so
//     chain lengths/precision match the old kernel). No fp64, ONE barrier,
//     acc[8], __launch_bounds__(256,8) targeting VGPR<=64 -> 32 waves/CU.
//   Fallback: old fused kernel if ws_size too small.

#define N2 32
#define L_LEN 4096
#define NTHREADS 256
#define PQS4 17            // padded row stride in float4 units
#define NJ 8               // j-values per block in the split sweep

typedef float v2 __attribute__((ext_vector_type(2)));

__device__ __forceinline__ v2 vfma(v2 a, v2 b, v2 c) {
  return __builtin_elementwise_fma(a, b, c);
}

// ---------------------------------------------------------------- kernel A
__global__ __launch_bounds__(256) void s4d_prep(
    const float* __restrict__ log_dt,      // (H,)
    const float* __restrict__ Cri,         // (H, N2, 2)
    const float* __restrict__ log_A_real,  // (H, N2)
    const float* __restrict__ A_imag,      // (H, N2)
    float4* __restrict__ ws0,              // (H*N2): (wr, wi, ckr, cki)
    float4* __restrict__ ws1,              // (H*N2): (w16r, w16i, W8r, W8i)
    float4* __restrict__ ws2,              // (H*N2): (Wr, Wi, p, -q)
    int total)
{
  const int i = blockIdx.x * 256 + threadIdx.x;
  if (i >= total) return;
  const int h = i >> 5;                    // N2 == 32
  const double dt = exp((double)log_dt[h]);
  const double Ar = -exp((double)log_A_real[i]);
  const double Ai = (double)A_imag[i];
  const double xr = dt * Ar;
  const double xi = dt * Ai;
  const double ex = exp(xr);
  const double wr = ex * cos(xi);          // w = exp(dtA)
  const double wi = ex * sin(xi);
  // Ck = 2 * Cc * (w-1)/A  via (w-1)*conj(A)/|A|^2
  const double nr = wr - 1.0, ni = wi;
  const double inv = 1.0 / (Ar * Ar + Ai * Ai);
  const double fr = (nr * Ar + ni * Ai) * inv;
  const double fi = (ni * Ar - nr * Ai) * inv;
  const double c0 = (double)Cri[i * 2 + 0];
  const double c1 = (double)Cri[i * 2 + 1];
  ws0[i] = make_float4((float)wr, (float)wi,
                       (float)(2.0 * (c0 * fr - c1 * fi)),
                       (float)(2.0 * (c0 * fi + c1 * fr)));
  double ar = wr, ai2 = wi;
#pragma unroll
  for (int k = 0; k < 4; ++k) {            // w^16
    const double tr = ar * ar - ai2 * ai2;
    const double ti = 2.0 * ar * ai2;
    ar = tr; ai2 = ti;
  }
  const float w16r = (float)ar, w16i = (float)ai2;
#pragma unroll
  for (int k = 0; k < 4; ++k) {            // w^256 = W
    const double tr = ar * ar - ai2 * ai2;
    const double ti = 2.0 * ar * ai2;
    ar = tr; ai2 = ti;
  }
  const double Wr = ar, Wi = ai2;
#pragma unroll
  for (int k = 0; k < 3; ++k) {            // w^2048 = W8
    const double tr = ar * ar - ai2 * ai2;
    const double ti = 2.0 * ar * ai2;
    ar = tr; ai2 = ti;
  }
  ws1[i] = make_float4(w16r, w16i, (float)ar, (float)ai2);
  ws2[i] = make_float4((float)Wr, (float)Wi,
                       (float)(2.0 * Wr), (float)(-(Wr * Wr + Wi * Wi)));
}

// ---------------------------------------------------------------- kernel B
__global__ __launch_bounds__(NTHREADS, 8) void s4d_sweep(
    const float4* __restrict__ ws0,
    const float4* __restrict__ ws1,
    const float4* __restrict__ ws2,
    float* __restrict__ out)
{
  const int bid = blockIdx.x;
  const int h = bid >> 1;
  const int s = bid & 1;                   // which half of L
  const int t = threadIdx.x;
  const int a = t >> 4;
  const int b = t & 15;

  __shared__ float2 s_w[N2], s_ck[N2];
  __shared__ float4 s_Wri[N2 / 2];         // (Wr0,Wr1,Wi0,Wi1) per pair
  __shared__ float4 s_Wpq[N2 / 2];         // (p0,p1,-q0,-q1)   per pair
  __shared__ float4 s_P[16 * PQS4];        // planar (Pr0,Pr1,Pi0,Pi1), pad 17
  __shared__ float4 s_Q[16 * PQS4];

  // ---- prep: wave 0 only (lanes 0-63); no barrier needed until step 3 ----
  float4 f1 = make_float4(0.f, 0.f, 0.f, 0.f);
  if (t < N2) {
    const int n = t;
    const float4 f0 = ws0[h * N2 + n];
    f1 = ws1[h * N2 + n];
    const float4 f2 = ws2[h * N2 + n];
    s_w[n] = make_float2(f0.x, f0.y);
    s_ck[n] = make_float2(f0.z, f0.w);
    float* Wri_f = (float*)s_Wri;
    float* Wpq_f = (float*)s_Wpq;
    const int pbase = (n >> 1) * 4 + (n & 1);
    Wri_f[pbase + 0] = f2.x;
    Wri_f[pbase + 2] = f2.y;
    Wpq_f[pbase + 0] = f2.z;
    Wpq_f[pbase + 2] = f2.w;
  }
  if (t < 64) {
    const int n = t & 31;
    const int comp = n & 1;
    const int np = n >> 1;
    if (t < 32) {
      float* Pf = (float*)s_P;
      const float gx = f1.x, gy = f1.y;    // w^16 (kept in regs from load)
      float pr, pi;
      if (s == 0) { pr = 1.0f; pi = 0.0f; }
      else        { pr = f1.z; pi = f1.w; }  // W8 = w^2048, fp64-accurate
#pragma unroll
      for (int aa = 0; aa < 16; ++aa) {    // P[aa][n] = W8^s * (w^16)^aa
        const int base = (aa * PQS4 + np) * 4 + comp;
        Pf[base + 0] = pr;
        Pf[base + 2] = pi;
        const float tr = fmaf(pr, gx, -(pi * gy));
        const float ti = fmaf(pr, gy, pi * gx);
        pr = tr; pi = ti;
      }
    } else {
      float* Qf = (float*)s_Q;
      const float2 w = s_w[n];             // same-wave LDS dep, compiler waits
      const float2 c = s_ck[n];
      float qr = c.x, qi = c.y;
#pragma unroll
      for (int bb = 0; bb < 16; ++bb) {    // Q[bb][n] = Ck * w^bb
        const int base = (bb * PQS4 + np) * 4 + comp;
        Qf[base + 0] = qr;
        Qf[base + 2] = qi;
        const float tr = fmaf(qr, w.x, -(qi * w.y));
        const float ti = fmaf(qr, w.y, qi * w.x);
        qr = tr; qi = ti;
      }
    }
  }
  __syncthreads();

  // ---- packed-pair recurrence sweep over NJ=8 j-values ----
  v2 acc[NJ];
#pragma unroll
  for (int j = 0; j < NJ; ++j) acc[j] = (v2){0.0f, 0.0f};

  const float4* Pa = s_P + a * PQS4;
  const float4* Qb = s_Q + b * PQS4;

#pragma unroll
  for (int np = 0; np < N2 / 2; ++np) {
    const float4 P4 = Pa[np];
    const float4 Q4 = Qb[np];
    const float4 Wri4 = s_Wri[np];
    const float4 Wpq4 = s_Wpq[np];
    const v2 Prp = (v2){P4.x, P4.y}, Pip = (v2){P4.z, P4.w};
    const v2 Qrp = (v2){Q4.x, Q4.y}, Qip = (v2){Q4.z, Q4.w};
    const v2 Wrp = (v2){Wri4.x, Wri4.y}, Wip = (v2){Wri4.z, Wri4.w};
    const v2 pp  = (v2){Wpq4.x, Wpq4.y}, mqp = (v2){Wpq4.z, Wpq4.w};

    const v2 Brp = vfma(Prp, Qrp, -(Pip * Qip));
    const v2 Bip = vfma(Prp, Qip, Pip * Qrp);
    v2 s0 = Brp;
    v2 s1 = vfma(Brp, Wrp, -(Bip * Wip));
    acc[0] += s0;
    acc[1] += s1;
#pragma unroll
    for (int j = 2; j < NJ; ++j) {
      const v2 s2 = vfma(pp, s1, mqp * s0);
      acc[j] += s2;
      s0 = s1; s1 = s2;
    }
  }

  float* o = out + (size_t)h * L_LEN + s * (L_LEN / 2) + t;
#pragma unroll
  for (int j = 0; j < NJ; ++j) o[j * NTHREADS] = acc[j].x + acc[j].y;
}

// ------------------------------------------------- fallback fused kernel (R6)
__global__ __launch_bounds__(NTHREADS, 4) void s4d_fused_kernel(
    const float* __restrict__ log_dt,
    const float* __restrict__ Cri,
    const float* __restrict__ log_A_real,
    const float* __restrict__ A_imag,
    float* __restrict__ out)
{
  const int h = blockIdx.x;
  const int t = threadIdx.x;
  const int a = t >> 4;
  const int b = t & 15;

  __shared__ float2 s_w[N2], s_w16[N2], s_ck[N2];
  __shared__ float4 s_Wri[N2 / 2];
  __shared__ float4 s_Wpq[N2 / 2];
  __shared__ float4 s_P[16 * PQS4];
  __shared__ float4 s_Q[16 * PQS4];

  if (t < N2) {
    const int n = t;
    const int idx = h * N2 + n;
    const double dt = exp((double)log_dt[h]);
    const double Ar = -exp((double)log_A_real[idx]);
    const double Ai = (double)A_imag[idx];
    const double xr = dt * Ar;
    const double xi = dt * Ai;
    const double ex = exp(xr);
    const double wr = ex * cos(xi);
    const double wi = ex * sin(xi);
    const double nr = wr - 1.0, ni = wi;
    const double inv = 1.0 / (Ar * Ar + Ai * Ai);
    const double fr = (nr * Ar + ni * Ai) * inv;
    const double fi = (ni * Ar - nr * Ai) * inv;
    const double c0 = (double)Cri[idx * 2 + 0];
    const double c1 = (double)Cri[idx * 2 + 1];
    s_ck[n] = make_float2((float)(2.0 * (c0 * fr - c1 * fi)),
                          (float)(2.0 * (c0 * fi + c1 * fr)));
    s_w[n] = make_float2((float)wr, (float)wi);
    double ar = wr, ai2 = wi;
#pragma unroll
    for (int k = 0; k < 4; ++k) {
      const double tr = ar * ar - ai2 * ai2;
      const double ti = 2.0 * ar * ai2;
      ar = tr; ai2 = ti;
    }
    s_w16[n] = make_float2((float)ar, (float)ai2);
#pragma unroll
    for (int k = 0; k < 4; ++k) {
      const double tr = ar * ar - ai2 * ai2;
      const double ti = 2.0 * ar * ai2;
      ar = tr; ai2 = ti;
    }
    float* Wri_f = (float*)s_Wri;
    float* Wpq_f = (float*)s_Wpq;
    const int pbase = (n >> 1) * 4 + (n & 1);
    Wri_f[pbase + 0] = (float)ar;
    Wri_f[pbase + 2] = (float)ai2;
    Wpq_f[pbase + 0] = (float)(2.0 * ar);
    Wpq_f[pbase + 2] = (float)(-(ar * ar + ai2 * ai2));
  }
  __syncthreads();

  if (t < 64) {
    const int n = t & 31;
    const int comp = n & 1;
    const int np = n >> 1;
    if (t < 32) {
      float* Pf = (float*)s_P;
      const float2 g = s_w16[n];
      float pr = 1.0f, pi = 0.0f;
#pragma unroll
      for (int aa = 0; aa < 16; ++aa) {
        const int base = (aa * PQS4 + np) * 4 + comp;
        Pf[base + 0] = pr;
        Pf[base + 2] = pi;
        const float tr = fmaf(pr, g.x, -(pi * g.y));
        const float ti = fmaf(pr, g.y, pi * g.x);
        pr = tr; pi = ti;
      }
    } else {
      float* Qf = (float*)s_Q;
      const float2 w = s_w[n];
      const float2 c = s_ck[n];
      float qr = c.x, qi = c.y;
#pragma unroll
      for (int bb = 0; bb < 16; ++bb) {
        const int base = (bb * PQS4 + np) * 4 + comp;
        Qf[base + 0] = qr;
        Qf[base + 2] = qi;
        const float tr = fmaf(qr, w.x, -(qi * w.y));
        const float ti = fmaf(qr, w.y, qi * w.x);
        qr = tr; qi = ti;
      }
    }
  }
  __syncthreads();

  v2 acc[16];
#pragma unroll
  for (int j = 0; j < 16; ++j) acc[j] = (v2){0.0f, 0.0f};

  const float4* Pa = s_P + a * PQS4;
  const float4* Qb = s_Q + b * PQS4;

#pragma unroll
  for (int np = 0; np < N2 / 2; ++np) {
    const float4 P4 = Pa[np];
    const float4 Q4 = Qb[np];
    const float4 Wri4 = s_Wri[np];
    const float4 Wpq4 = s_Wpq[np];
    const v2 Prp = (v2){P4.x, P4.y}, Pip = (v2){P4.z, P4.w};
    const v2 Qrp = (v2){Q4.x, Q4.y}, Qip = (v2){Q4.z, Q4.w};
    const v2 Wrp = (v2){Wri4.x, Wri4.y}, Wip = (v2){Wri4.z, Wri4.w};
    const v2 pp  = (v2){Wpq4.x, Wpq4.y}, mqp = (v2){Wpq4.z, Wpq4.w};

    const v2 Brp = vfma(Prp, Qrp, -(Pip * Qip));
    const v2 Bip = vfma(Prp, Qip, Pip * Qrp);
    v2 s0 = Brp;
    v2 s1 = vfma(Brp, Wrp, -(Bip * Wip));
    acc[0] += s0;
    acc[1] += s1;
#pragma unroll
    for (int j = 2; j < 16; ++j) {
      const v2 s2 = vfma(pp, s1, mqp * s0);
      acc[j] += s2;
      s0 = s1; s1 = s2;
    }
  }

  float* o = out + (size_t)h * L_LEN + t;
#pragma unroll
  for (int j = 0; j < 16; ++j) o[j * NTHREADS] = acc[j].x + acc[j].y;
}

extern "C" void kernel_launch(void* const* d_in, const int* in_sizes, int n_in,
                              void* d_out, int out_size, void* d_ws, size_t ws_size,
                              hipStream_t stream) {
  const float* log_dt     = (const float*)d_in[0];
  const float* Cri        = (const float*)d_in[1];
  const float* log_A_real = (const float*)d_in[2];
  const float* A_imag     = (const float*)d_in[3];
  float* out = (float*)d_out;
  const int H = in_sizes[0];
  const int total = H * N2;
  const size_t need = (size_t)total * 3 * sizeof(float4);

  if (d_ws != nullptr && ws_size >= need) {
    float4* ws0 = (float4*)d_ws;
    float4* ws1 = ws0 + total;
    float4* ws2 = ws1 + total;
    s4d_prep<<<dim3((total + 255) / 256), dim3(256), 0, stream>>>(
        log_dt, Cri, log_A_real, A_imag, ws0, ws1, ws2, total);
    s4d_sweep<<<dim3(H * 2), dim3(NTHREADS), 0, stream>>>(ws0, ws1, ws2, out);
  } else {
    s4d_fused_kernel<<<dim3(H), dim3(NTHREADS), 0, stream>>>(
        log_dt, Cri, log_A_real, A_imag, out);
  }
}

// Round 4
// 75.148 us; speedup vs baseline: 1.0411x; 1.0411x over previous
//
#include <hip/hip_runtime.h>
#include <math.h>

// S4D kernel generation: K[h,l] = 2*Re( sum_n Ck[h,n] * exp(dtA[h,n]*l) )
// H=1024, N2=32, L=4096. Output (H,L) fp32.
//
// Journal:
//  R5: pad P/Q stride 16->17 f4 (bank conflicts): 77.4->76.3.
//  R6: planar pair-packing + compiler v2 math:    76.3->74.9.
//  R7: two-kernel split (prep + 2x-occupancy sweep): 74.9->78.2 REGRESSION.
//      -> occupancy/prelude-convoy theory dead; extra dispatch costs ~3us.
//  Model (H1): timed region = 256MiB poison fill (~42us) + ~20-25us of tiny
//      harness memset/restore dispatches + kernel (~7-10us). Kernel is near
//      its LDS+VALU floor (~5-6us); optimize dispatch count + barriers.
//  R8 (this round): single fused dispatch again, ONE barrier:
//      wave 0 does fp64 prep (lanes 0-31) and passes w/Ck to lanes 32-63 via
//      __shfl (register cross-lane, no LDS, no barrier); lanes 0-31 build the
//      P table (w16 kept in registers), lanes 32-63 build Q. Dropped
//      s_w/s_w16/s_ck LDS arrays and the first __syncthreads. fp64 math
//      bit-identical to R6 -> absmax unchanged.

#define N2 32
#define L_LEN 4096
#define NTHREADS 256
#define PQS4 17            // padded row stride in float4 units

typedef float v2 __attribute__((ext_vector_type(2)));

__device__ __forceinline__ v2 vfma(v2 a, v2 b, v2 c) {
  return __builtin_elementwise_fma(a, b, c);
}

__global__ __launch_bounds__(NTHREADS, 4) void s4d_fused_kernel(
    const float* __restrict__ log_dt,      // (H,)
    const float* __restrict__ Cri,         // (H, N2, 2)
    const float* __restrict__ log_A_real,  // (H, N2)
    const float* __restrict__ A_imag,      // (H, N2)
    float* __restrict__ out)               // (H, L)
{
  const int h = blockIdx.x;
  const int t = threadIdx.x;
  const int a = t >> 4;
  const int b = t & 15;

  __shared__ float4 s_Wri[N2 / 2];      // [np] = (Wr0, Wr1, Wi0, Wi1)
  __shared__ float4 s_Wpq[N2 / 2];      // [np] = (p0, p1, -q0, -q1)
  __shared__ float4 s_P[16 * PQS4];     // [a][np] = (Pr0,Pr1,Pi0,Pi1), pad 17
  __shared__ float4 s_Q[16 * PQS4];     // [b][np] = (Qr0,Qr1,Qi0,Qi1), pad 17

  // ---- wave 0 only: fp64 prep + P/Q table build, ONE barrier total ----
  if (t < 64) {
    float wr_f = 0.f, wi_f = 0.f, ckr_f = 0.f, cki_f = 0.f;
    float w16r = 0.f, w16i = 0.f;
    if (t < N2) {
      const int n = t;
      const int idx = h * N2 + n;
      const double dt = exp((double)log_dt[h]);
      const double Ar = -exp((double)log_A_real[idx]);
      const double Ai = (double)A_imag[idx];
      const double xr = dt * Ar;
      const double xi = dt * Ai;
      const double ex = exp(xr);
      const double wr = ex * cos(xi);   // w = exp(dtA)
      const double wi = ex * sin(xi);
      // Ck = 2 * Cc * (w-1)/A  via (w-1)*conj(A)/|A|^2
      const double nr = wr - 1.0, ni = wi;
      const double inv = 1.0 / (Ar * Ar + Ai * Ai);
      const double fr = (nr * Ar + ni * Ai) * inv;
      const double fi = (ni * Ar - nr * Ai) * inv;
      const double c0 = (double)Cri[idx * 2 + 0];
      const double c1 = (double)Cri[idx * 2 + 1];
      ckr_f = (float)(2.0 * (c0 * fr - c1 * fi));
      cki_f = (float)(2.0 * (c0 * fi + c1 * fr));
      wr_f = (float)wr;
      wi_f = (float)wi;
      double ar = wr, ai2 = wi;
#pragma unroll
      for (int k = 0; k < 4; ++k) {     // w^16
        const double tr = ar * ar - ai2 * ai2;
        const double ti = 2.0 * ar * ai2;
        ar = tr; ai2 = ti;
      }
      w16r = (float)ar; w16i = (float)ai2;
#pragma unroll
      for (int k = 0; k < 4; ++k) {     // w^256 = W
        const double tr = ar * ar - ai2 * ai2;
        const double ti = 2.0 * ar * ai2;
        ar = tr; ai2 = ti;
      }
      // planar per-pair W tables: component (n&1) of pair (n>>1)
      float* Wri_f = (float*)s_Wri;
      float* Wpq_f = (float*)s_Wpq;
      const int pbase = (n >> 1) * 4 + (n & 1);
      Wri_f[pbase + 0] = (float)ar;                        // Wr
      Wri_f[pbase + 2] = (float)ai2;                       // Wi
      Wpq_f[pbase + 0] = (float)(2.0 * ar);                // p
      Wpq_f[pbase + 2] = (float)(-(ar * ar + ai2 * ai2));  // -q
    }
    // pass w, Ck from lane n to lane 32+n in-register (no LDS, no barrier)
    const int src = t & 31;
    const float wxr = __shfl(wr_f, src);
    const float wxi = __shfl(wi_f, src);
    const float cxr = __shfl(ckr_f, src);
    const float cxi = __shfl(cki_f, src);

    const int n = t & 31;
    const int comp = n & 1;
    const int np = n >> 1;
    if (t < 32) {
      float* Pf = (float*)s_P;
      float pr = 1.0f, pi = 0.0f;
#pragma unroll
      for (int aa = 0; aa < 16; ++aa) { // P[aa][n] = (w^16)^aa
        const int base = (aa * PQS4 + np) * 4 + comp;
        Pf[base + 0] = pr;
        Pf[base + 2] = pi;
        const float tr = fmaf(pr, w16r, -(pi * w16i));
        const float ti = fmaf(pr, w16i, pi * w16r);
        pr = tr; pi = ti;
      }
    } else {
      float* Qf = (float*)s_Q;
      float qr = cxr, qi = cxi;
#pragma unroll
      for (int bb = 0; bb < 16; ++bb) { // Q[bb][n] = Ck * w^bb
        const int base = (bb * PQS4 + np) * 4 + comp;
        Qf[base + 0] = qr;
        Qf[base + 2] = qi;
        const float tr = fmaf(qr, wxr, -(qi * wxi));
        const float ti = fmaf(qr, wxi, qi * wxr);
        qr = tr; qi = ti;
      }
    }
  }
  __syncthreads();

  // ---- packed-pair recurrence sweep (pure compiler v2 math) ----
  v2 acc[16];
#pragma unroll
  for (int j = 0; j < 16; ++j) acc[j] = (v2){0.0f, 0.0f};

  const float4* Pa = s_P + a * PQS4;
  const float4* Qb = s_Q + b * PQS4;

#pragma unroll
  for (int np = 0; np < N2 / 2; ++np) {
    const float4 P4 = Pa[np];           // (Pr0,Pr1,Pi0,Pi1)
    const float4 Q4 = Qb[np];           // (Qr0,Qr1,Qi0,Qi1)
    const float4 Wri4 = s_Wri[np];      // (Wr0,Wr1,Wi0,Wi1) uniform
    const float4 Wpq4 = s_Wpq[np];      // (p0,p1,-q0,-q1)   uniform
    const v2 Prp = (v2){P4.x, P4.y}, Pip = (v2){P4.z, P4.w};
    const v2 Qrp = (v2){Q4.x, Q4.y}, Qip = (v2){Q4.z, Q4.w};
    const v2 Wrp = (v2){Wri4.x, Wri4.y}, Wip = (v2){Wri4.z, Wri4.w};
    const v2 pp  = (v2){Wpq4.x, Wpq4.y}, mqp = (v2){Wpq4.z, Wpq4.w};

    // B = P*Q (complex, per packed mode)
    const v2 Brp = vfma(Prp, Qrp, -(Pip * Qip));
    const v2 Bip = vfma(Prp, Qip, Pip * Qrp);
    // s0 = Re(B), s1 = Re(B*W)
    v2 s0 = Brp;
    v2 s1 = vfma(Brp, Wrp, -(Bip * Wip));
    acc[0] += s0;
    acc[1] += s1;
#pragma unroll
    for (int j = 2; j < 16; ++j) {
      const v2 s2 = vfma(pp, s1, mqp * s0);
      acc[j] += s2;
      s0 = s1; s1 = s2;
    }
  }

  float* o = out + (size_t)h * L_LEN + t;  // l = 256*j + t
#pragma unroll
  for (int j = 0; j < 16; ++j) o[j * NTHREADS] = acc[j].x + acc[j].y;
}

extern "C" void kernel_launch(void* const* d_in, const int* in_sizes, int n_in,
                              void* d_out, int out_size, void* d_ws, size_t ws_size,
                              hipStream_t stream) {
  const float* log_dt     = (const float*)d_in[0];
  const float* Cri        = (const float*)d_in[1];
  const float* log_A_real = (const float*)d_in[2];
  const float* A_imag     = (const float*)d_in[3];
  float* out = (float*)d_out;
  const int H = in_sizes[0];

  s4d_fused_kernel<<<dim3(H), dim3(NTHREADS), 0, stream>>>(
      log_dt, Cri, log_A_real, A_imag, out);
}